// Round 12
// baseline (191.548 us; speedup 1.0000x reference)
//
#include <hip/hip_runtime.h>

// Problem constants (B,C,H,W = 8,64,128,128; K=3)
#define BATCH 8
#define CIN   64
#define HW    16384      // 128*128
#define CK    576        // CIN*K2

typedef __attribute__((ext_vector_type(8))) short bf16x8;
typedef __attribute__((ext_vector_type(4))) float f32x4;
typedef __attribute__((ext_vector_type(2))) float f32x2;

__device__ inline unsigned short f2bf(float f) {
    unsigned int u = __builtin_bit_cast(unsigned int, f);
    u += 0x7FFFu + ((u >> 16) & 1u);          // round-to-nearest-even
    return (unsigned short)(u >> 16);
}
__device__ inline float bf2f(unsigned short u) {
    return __builtin_bit_cast(float, (unsigned)u << 16);
}
__device__ inline f32x2 upk2(unsigned u) {    // two bf16 in a dword -> f32x2
    f32x2 r;
    r[0] = __builtin_bit_cast(float, u << 16);
    r[1] = __builtin_bit_cast(float, u & 0xFFFF0000u);
    return r;
}
__device__ inline unsigned pk2bf(f32x2 s) {   // manual RNE pack (R8/R11 codegen)
    return (unsigned)f2bf(s[0]) | ((unsigned)f2bf(s[1]) << 16);
}

// ---------------- ws layout (ushort units) ----------------
// wpack  [18][4][64][8]  deform A-frags      at 0          (36864)
// wcpack [18][2][64][8]  conv A-frags        at 36864      (18432)
// xT     [B][HW][64]     NHWC bf16 input     at 55296      (8388608)

// Fused prep (blocks 0-143) + NCHW->NHWC bf16 transpose (all 2048 blocks).
__global__ __launch_bounds__(256) void prep_transpose(
        const float* __restrict__ x, const float* __restrict__ ow,
        const float* __restrict__ mw, const float* __restrict__ dw,
        unsigned short* __restrict__ wpack, unsigned short* __restrict__ wcpack,
        unsigned short* __restrict__ xT) {
    int t = threadIdx.x, blk = blockIdx.x;
    // ---- transpose part
    {
        int b = blk & 7, r2 = blk >> 3;
        int h = r2 >> 1, hf = r2 & 1;
        int gx = (hf << 6) + (t & 63);
        int w = t >> 6;
        int pix = (h << 7) + gx;
        const float* __restrict__ xb = x + (b * CIN) * HW + pix;
        bf16x8 lo, hi;
#pragma unroll
        for (int i = 0; i < 8; i++) lo[i] = (short)f2bf(xb[(w * 16 + i) * HW]);
#pragma unroll
        for (int i = 0; i < 8; i++) hi[i] = (short)f2bf(xb[(w * 16 + 8 + i) * HW]);
        unsigned short* dst = xT + ((b * HW + pix) << 6) + w * 16;
        *(bf16x8*)dst = lo;
        *(bf16x8*)(dst + 8) = hi;
    }
    // ---- prep part (first 144 blocks)
    int g = blk * 256 + t;
    if (g < 18 * 4 * 64 * 8) {           // deform weights: dw[o][c][tap]
        int j = g & 7, lane = (g >> 3) & 63, ot = (g >> 9) & 3, gks = g >> 11;
        int o = ot * 16 + (lane & 15);
        int s = gks * 32 + ((lane >> 4) & 3) * 8 + j;
        int c = s & 63, tap = s >> 6;
        wpack[g] = f2bf(dw[o * CK + c * 9 + tap]);
    }
    if (g < 18 * 2 * 64 * 8) {           // conv weights: rows 0-17 ow, 18-26 mw
        int j = g & 7, lane = (g >> 3) & 63, ot = (g >> 9) & 1, gks = g >> 10;
        int o = ot * 16 + (lane & 15);
        int s = gks * 32 + ((lane >> 4) & 3) * 8 + j;
        int c = s & 63, tap = s >> 6;
        float v = 0.f;
        if (o < 18)      v = ow[(o * 64 + c) * 9 + tap];
        else if (o < 27) v = mw[((o - 18) * 64 + c) * 9 + tap];
        wcpack[g] = f2bf(v);
    }
}

// Fused offset/mask conv + deformable conv. Block = 64 px (half row).
// Stage 1: halo tile -> LDS.  Phase A: conv MFMA from tile -> omrow LDS.
// Phase B: bilinear params -> per-lane REGISTERS (no LDS).
// Phase C: LDS-FREE — each lane loads its own pixel's 4 corner rows
// (quad-sliced b128, consecutive-px lanes hit consecutive 128B rows) and
// feeds MFMA directly. No gather buffer, no barriers, no bank conflicts.
// LDS 32,608 B -> 5 blocks/CU by LDS; VGPR ~130 -> 4 waves/SIMD.
__global__ __launch_bounds__(256, 3) void fused_kernel(
        const unsigned short* __restrict__ xT, const unsigned short* __restrict__ wcpack,
        const unsigned short* __restrict__ wpack,
        const float* __restrict__ ob, const float* __restrict__ mb,
        const float* __restrict__ dbv, float* __restrict__ out) {
    __shared__ unsigned short buf[14256];      // 28,512 B: halo tile
    __shared__ unsigned short omrow[2048];     //  4,096 B

    int t = threadIdx.x;
    int lane = t & 63, pt = t >> 6, quad = lane >> 4, n = lane & 15;
    int blk = blockIdx.x;
    int b = blk & 7, r2 = blk >> 3;
    int h = r2 >> 1, hf = r2 & 1;
    int px0 = hf << 6;
    int pxl = (pt << 4) + n;          // this lane's pixel within the 64-px block
    int gx  = px0 + pxl;

    const unsigned short* __restrict__ xtb = xT + ((b * HW) << 6);
    const short zs = 0;
    const bf16x8 zv = {zs, zs, zs, zs, zs, zs, zs, zs};

    // ========== Stage 1: halo tile (rows h-1..h+1, cols px0-1..px0+64) ==========
    for (int i = t; i < 1584; i += 256) {       // 198 rows x 8 slices
        int s  = i & 7;
        int rc = i >> 3;                        // 0..197
        int r  = rc / 66, col = rc - r * 66;
        int gy  = h - 1 + r;
        int gxc = px0 - 1 + col;
        bf16x8 v = zv;
        if ((unsigned)gy < 128u && (unsigned)gxc < 128u)
            v = *(const bf16x8*)(xtb + (((gy << 7) + gxc) << 6) + (s << 3));
        *(bf16x8*)&buf[rc * 72 + (s << 3)] = v;
    }
    __syncthreads();

    // ========== Phase A: offset/mask conv from LDS tile ==========
    {
        f32x4 acc0 = {0.f, 0.f, 0.f, 0.f}, acc1 = {0.f, 0.f, 0.f, 0.f};
#pragma unroll
        for (int tap = 0; tap < 9; tap++) {
            int r = tap / 3, cm = tap % 3;
            const unsigned short* srcA = &buf[(r * 66 + pxl + cm) * 72];
#pragma unroll
            for (int kk = 0; kk < 2; kk++) {
                bf16x8 bfrag = *(const bf16x8*)(srcA + (kk << 5) + (quad << 3));
                int gks = tap * 2 + kk;
                bf16x8 a0 = *(const bf16x8*)(wcpack + ((gks * 2 + 0) * 64 + lane) * 8);
                bf16x8 a1 = *(const bf16x8*)(wcpack + ((gks * 2 + 1) * 64 + lane) * 8);
                acc0 = __builtin_amdgcn_mfma_f32_16x16x32_bf16(a0, bfrag, acc0, 0, 0, 0);
                acc1 = __builtin_amdgcn_mfma_f32_16x16x32_bf16(a1, bfrag, acc1, 0, 0, 0);
            }
        }
        // epilogue -> omrow LDS. D[px=lane&15][o=quad*4+r] (+16 for acc1)
        {
            unsigned short p[4];
#pragma unroll
            for (int r = 0; r < 4; r++) p[r] = f2bf(acc0[r] + ob[quad * 4 + r]);
            uint2 u;
            u.x = (unsigned)p[0] | ((unsigned)p[1] << 16);
            u.y = (unsigned)p[2] | ((unsigned)p[3] << 16);
            *(uint2*)&omrow[pxl * 32 + quad * 4] = u;
        }
        {
            unsigned short p[4];
#pragma unroll
            for (int r = 0; r < 4; r++) {
                int o = 16 + quad * 4 + r;
                float v = acc1[r];
                if (o < 18) v += ob[o];
                else if (o < 27) { v += mb[o - 18]; v = 1.f / (1.f + __expf(-v)); }
                else v = 0.f;
                p[r] = f2bf(v);
            }
            uint2 u;
            u.x = (unsigned)p[0] | ((unsigned)p[1] << 16);
            u.y = (unsigned)p[2] | ((unsigned)p[3] << 16);
            *(uint2*)&omrow[pxl * 32 + 16 + quad * 4] = u;
        }
    }
    __syncthreads();

    // ========== Phase B: bilinear params -> per-lane registers ==========
    float w00[9], w01[9], w10[9], w11[9];
    int pk[9];
#pragma unroll
    for (int k = 0; k < 9; k++) {
        float dy = bf2f(omrow[pxl * 32 + 2 * k]);
        float dx = bf2f(omrow[pxl * 32 + 2 * k + 1]);
        float mk = bf2f(omrow[pxl * 32 + 18 + k]);
        float py  = (float)h  + (float)(k / 3 - 1) + dy;
        float pxx = (float)gx + (float)(k % 3 - 1) + dx;
        float fy = floorf(py), fx = floorf(pxx);
        float ly = py - fy, lx = pxx - fx;
        int y0 = (int)fy, x0 = (int)fx;
        bool y0v = (unsigned)y0 < 128u, y1v = (unsigned)(y0 + 1) < 128u;
        bool x0v = (unsigned)x0 < 128u, x1v = (unsigned)(x0 + 1) < 128u;
        w00[k] = (y0v && x0v) ? (1.f - ly) * (1.f - lx) * mk : 0.f;
        w01[k] = (y0v && x1v) ? (1.f - ly) * lx * mk : 0.f;
        w10[k] = (y1v && x0v) ? ly * (1.f - lx) * mk : 0.f;
        w11[k] = (y1v && x1v) ? ly * lx * mk : 0.f;
        int y0c = min(max(y0, 0), 127), x0c = min(max(x0, 0), 127);
        int dxb = (x0 >= 0 && x0 < 127) ? 1 : 0;
        int dyb = (y0 >= 0 && y0 < 127) ? 1 : 0;
        pk[k] = ((y0c << 7) + x0c) | (dxb << 14) | (dyb << 15);
    }

    // ========== Phase C: deform MFMA, LDS-free direct corner loads ==========
    f32x4 acc[4];
#pragma unroll
    for (int ot = 0; ot < 4; ot++) acc[ot] = (f32x4){0.f, 0.f, 0.f, 0.f};

#pragma unroll
    for (int tap = 0; tap < 9; tap++) {
        int p = pk[tap];
        int base = p & 0x3FFF;
        int dxb  = (p >> 14) & 1;
        int dyo  = ((p >> 15) & 1) << 7;
        const unsigned short* __restrict__ r00 = xtb + (base << 6);
        const unsigned short* __restrict__ r01 = xtb + ((base + dxb) << 6);
        const unsigned short* __restrict__ r10 = xtb + ((base + dyo) << 6);
        const unsigned short* __restrict__ r11 = xtb + ((base + dyo + dxb) << 6);
        f32x2 W0 = {w00[tap], w00[tap]}, W1 = {w01[tap], w01[tap]};
        f32x2 W2 = {w10[tap], w10[tap]}, W3 = {w11[tap], w11[tap]};
#pragma unroll
        for (int kk = 0; kk < 2; kk++) {
            int co = (kk << 5) + (quad << 3);
            bf16x8 v00 = *(const bf16x8*)(r00 + co);
            bf16x8 v01 = *(const bf16x8*)(r01 + co);
            bf16x8 v10 = *(const bf16x8*)(r10 + co);
            bf16x8 v11 = *(const bf16x8*)(r11 + co);
            const unsigned* u00 = (const unsigned*)&v00;
            const unsigned* u01 = (const unsigned*)&v01;
            const unsigned* u10 = (const unsigned*)&v10;
            const unsigned* u11 = (const unsigned*)&v11;
            bf16x8 bfrag;
            unsigned* bu = (unsigned*)&bfrag;
#pragma unroll
            for (int jj = 0; jj < 4; jj++) {
                f32x2 s2 = upk2(u00[jj]) * W0 + upk2(u01[jj]) * W1
                         + upk2(u10[jj]) * W2 + upk2(u11[jj]) * W3;
                bu[jj] = pk2bf(s2);
            }
            int gks = tap * 2 + kk;
#pragma unroll
            for (int ot = 0; ot < 4; ot++) {
                bf16x8 af = *(const bf16x8*)(wpack + ((gks * 4 + ot) * 64 + lane) * 8);
                acc[ot] = __builtin_amdgcn_mfma_f32_16x16x32_bf16(af, bfrag, acc[ot], 0, 0, 0);
            }
        }
    }

    // ---- epilogue: D col(lane&15)=px, row = ot*16 + quad*4 + r = o
    int opix = (h << 7) + px0 + (pt << 4) + n;
#pragma unroll
    for (int ot = 0; ot < 4; ot++) {
#pragma unroll
        for (int r = 0; r < 4; r++) {
            int o = ot * 16 + quad * 4 + r;
            out[(b * 64 + o) * HW + opix] = acc[ot][r] + dbv[o];
        }
    }
}

extern "C" void kernel_launch(void* const* d_in, const int* in_sizes, int n_in,
                              void* d_out, int out_size, void* d_ws, size_t ws_size,
                              hipStream_t stream) {
    const float* x   = (const float*)d_in[0];
    const float* ow  = (const float*)d_in[1];
    const float* ob  = (const float*)d_in[2];
    const float* mw  = (const float*)d_in[3];
    const float* mb  = (const float*)d_in[4];
    const float* dw  = (const float*)d_in[5];
    const float* dbv = (const float*)d_in[6];
    float* out = (float*)d_out;

    unsigned short* wpack  = (unsigned short*)d_ws;          // 36864
    unsigned short* wcpack = wpack + 36864;                  // 18432
    unsigned short* xT     = wpack + 55296;                  // 8388608

    prep_transpose<<<2048, 256, 0, stream>>>(x, ow, mw, dw, wpack, wcpack, xT);
    fused_kernel<<<2048, 256, 0, stream>>>(xT, wcpack, wpack, ob, mb, dbv, out);
}

// Round 13
// 170.733 us; speedup vs baseline: 1.1219x; 1.1219x over previous
//
#include <hip/hip_runtime.h>

// Problem constants (B,C,H,W = 8,64,128,128; K=3)
#define BATCH 8
#define CIN   64
#define HW    16384      // 128*128
#define CK    576        // CIN*K2

typedef __attribute__((ext_vector_type(8))) short bf16x8;
typedef __attribute__((ext_vector_type(4))) float f32x4;
typedef __attribute__((ext_vector_type(2))) float f32x2;

__device__ inline unsigned short f2bf(float f) {
    unsigned int u = __builtin_bit_cast(unsigned int, f);
    u += 0x7FFFu + ((u >> 16) & 1u);          // round-to-nearest-even
    return (unsigned short)(u >> 16);
}
__device__ inline float bf2f(unsigned short u) {
    return __builtin_bit_cast(float, (unsigned)u << 16);
}
__device__ inline f32x2 upk2(unsigned u) {    // two bf16 in a dword -> f32x2
    f32x2 r;
    r[0] = __builtin_bit_cast(float, u << 16);
    r[1] = __builtin_bit_cast(float, u & 0xFFFF0000u);
    return r;
}
__device__ inline unsigned pk2bf(f32x2 s) {   // manual RNE pack (R8/R11 codegen)
    return (unsigned)f2bf(s[0]) | ((unsigned)f2bf(s[1]) << 16);
}

// ---------------- ws layout (ushort units) ----------------
// wpack  [18][4][64][8]  deform A-frags      at 0          (36864)
// wcpack [18][2][64][8]  conv A-frags        at 36864      (18432)
// xT     [B][HW][64]     NHWC bf16 input     at 55296      (8388608)

// Fused prep (blocks 0-143) + NCHW->NHWC bf16 transpose (all 2048 blocks).
__global__ __launch_bounds__(256) void prep_transpose(
        const float* __restrict__ x, const float* __restrict__ ow,
        const float* __restrict__ mw, const float* __restrict__ dw,
        unsigned short* __restrict__ wpack, unsigned short* __restrict__ wcpack,
        unsigned short* __restrict__ xT) {
    int t = threadIdx.x, blk = blockIdx.x;
    // ---- transpose part
    {
        int b = blk & 7, r2 = blk >> 3;
        int h = r2 >> 1, hf = r2 & 1;
        int gx = (hf << 6) + (t & 63);
        int w = t >> 6;
        int pix = (h << 7) + gx;
        const float* __restrict__ xb = x + (b * CIN) * HW + pix;
        bf16x8 lo, hi;
#pragma unroll
        for (int i = 0; i < 8; i++) lo[i] = (short)f2bf(xb[(w * 16 + i) * HW]);
#pragma unroll
        for (int i = 0; i < 8; i++) hi[i] = (short)f2bf(xb[(w * 16 + 8 + i) * HW]);
        unsigned short* dst = xT + ((b * HW + pix) << 6) + w * 16;
        *(bf16x8*)dst = lo;
        *(bf16x8*)(dst + 8) = hi;
    }
    // ---- prep part (first 144 blocks)
    int g = blk * 256 + t;
    if (g < 18 * 4 * 64 * 8) {           // deform weights: dw[o][c][tap]
        int j = g & 7, lane = (g >> 3) & 63, ot = (g >> 9) & 3, gks = g >> 11;
        int o = ot * 16 + (lane & 15);
        int s = gks * 32 + ((lane >> 4) & 3) * 8 + j;
        int c = s & 63, tap = s >> 6;
        wpack[g] = f2bf(dw[o * CK + c * 9 + tap]);
    }
    if (g < 18 * 2 * 64 * 8) {           // conv weights: rows 0-17 ow, 18-26 mw
        int j = g & 7, lane = (g >> 3) & 63, ot = (g >> 9) & 1, gks = g >> 10;
        int o = ot * 16 + (lane & 15);
        int s = gks * 32 + ((lane >> 4) & 3) * 8 + j;
        int c = s & 63, tap = s >> 6;
        float v = 0.f;
        if (o < 18)      v = ow[(o * 64 + c) * 9 + tap];
        else if (o < 27) v = mw[((o - 18) * 64 + c) * 9 + tap];
        wcpack[g] = f2bf(v);
    }
}

// Fused offset/mask conv + deformable conv. Block = 64 px (half row).
// Phase C gather does the Y-interpolation: lanes load top+bottom corner rows
// (coalesced), combine with bf16 wy-pair from wytab, write ONE row to LDS.
// Consumer reads 2 rows/kk (was 4) and applies x-weights from registers.
// LDS 37,216 B -> 4 blocks/CU. Depth-1 register prefetch kept (R11).
__global__ __launch_bounds__(256, 3) void fused_kernel(
        const unsigned short* __restrict__ xT, const unsigned short* __restrict__ wcpack,
        const unsigned short* __restrict__ wpack,
        const float* __restrict__ ob, const float* __restrict__ mb,
        const float* __restrict__ dbv, float* __restrict__ out) {
    __shared__ unsigned short buf[14256];      // 28,512 B: tile UNION gather (9280)
    __shared__ unsigned short omrow[2048];     //  4,096 B
    __shared__ int ptab[576];                  //  2,304 B
    __shared__ unsigned wytab[576];            //  2,304 B: packed (wy0,wy1) bf16

    int t = threadIdx.x;
    int lane = t & 63, pt = t >> 6, quad = lane >> 4, n = lane & 15;
    int blk = blockIdx.x;
    int b = blk & 7, r2 = blk >> 3;
    int h = r2 >> 1, hf = r2 & 1;
    int px0 = hf << 6;
    int pxl = (pt << 4) + n;          // this lane's pixel within the 64-px block
    int gx  = px0 + pxl;

    const unsigned short* __restrict__ xtb = xT + ((b * HW) << 6);
    const short zs = 0;
    const bf16x8 zv = {zs, zs, zs, zs, zs, zs, zs, zs};

    // ========== Stage 1: halo tile (rows h-1..h+1, cols px0-1..px0+64) ==========
    for (int i = t; i < 1584; i += 256) {       // 198 rows x 8 slices
        int s  = i & 7;
        int rc = i >> 3;                        // 0..197
        int r  = rc / 66, col = rc - r * 66;
        int gy  = h - 1 + r;
        int gxc = px0 - 1 + col;
        bf16x8 v = zv;
        if ((unsigned)gy < 128u && (unsigned)gxc < 128u)
            v = *(const bf16x8*)(xtb + (((gy << 7) + gxc) << 6) + (s << 3));
        *(bf16x8*)&buf[rc * 72 + (s << 3)] = v;
    }
    __syncthreads();

    // ========== Phase A: offset/mask conv from LDS tile ==========
    {
        f32x4 acc0 = {0.f, 0.f, 0.f, 0.f}, acc1 = {0.f, 0.f, 0.f, 0.f};
#pragma unroll
        for (int tap = 0; tap < 9; tap++) {
            int r = tap / 3, cm = tap % 3;
            const unsigned short* srcA = &buf[(r * 66 + pxl + cm) * 72];
#pragma unroll
            for (int kk = 0; kk < 2; kk++) {
                bf16x8 bfrag = *(const bf16x8*)(srcA + (kk << 5) + (quad << 3));
                int gks = tap * 2 + kk;
                bf16x8 a0 = *(const bf16x8*)(wcpack + ((gks * 2 + 0) * 64 + lane) * 8);
                bf16x8 a1 = *(const bf16x8*)(wcpack + ((gks * 2 + 1) * 64 + lane) * 8);
                acc0 = __builtin_amdgcn_mfma_f32_16x16x32_bf16(a0, bfrag, acc0, 0, 0, 0);
                acc1 = __builtin_amdgcn_mfma_f32_16x16x32_bf16(a1, bfrag, acc1, 0, 0, 0);
            }
        }
        // epilogue -> omrow LDS. D[px=lane&15][o=quad*4+r] (+16 for acc1)
        {
            unsigned short p[4];
#pragma unroll
            for (int r = 0; r < 4; r++) p[r] = f2bf(acc0[r] + ob[quad * 4 + r]);
            uint2 u;
            u.x = (unsigned)p[0] | ((unsigned)p[1] << 16);
            u.y = (unsigned)p[2] | ((unsigned)p[3] << 16);
            *(uint2*)&omrow[pxl * 32 + quad * 4] = u;
        }
        {
            unsigned short p[4];
#pragma unroll
            for (int r = 0; r < 4; r++) {
                int o = 16 + quad * 4 + r;
                float v = acc1[r];
                if (o < 18) v += ob[o];
                else if (o < 27) { v += mb[o - 18]; v = 1.f / (1.f + __expf(-v)); }
                else v = 0.f;
                p[r] = f2bf(v);
            }
            uint2 u;
            u.x = (unsigned)p[0] | ((unsigned)p[1] << 16);
            u.y = (unsigned)p[2] | ((unsigned)p[3] << 16);
            *(uint2*)&omrow[pxl * 32 + 16 + quad * 4] = u;
        }
    }
    __syncthreads();

    // ========== Phase B: params. x-weights (mask-premult) -> regs;
    //            y-weights (bf16 pair) + corner idx -> LDS tables ==========
    float wx0m[9], wx1m[9];
#pragma unroll
    for (int k = 0; k < 9; k++) {
        float dy = bf2f(omrow[pxl * 32 + 2 * k]);
        float dx = bf2f(omrow[pxl * 32 + 2 * k + 1]);
        float mk = bf2f(omrow[pxl * 32 + 18 + k]);
        float py  = (float)h  + (float)(k / 3 - 1) + dy;
        float pxx = (float)gx + (float)(k % 3 - 1) + dx;
        float fy = floorf(py), fx = floorf(pxx);
        float ly = py - fy, lx = pxx - fx;
        int y0 = (int)fy, x0 = (int)fx;
        bool y0v = (unsigned)y0 < 128u, y1v = (unsigned)(y0 + 1) < 128u;
        bool x0v = (unsigned)x0 < 128u, x1v = (unsigned)(x0 + 1) < 128u;
        wx0m[k] = x0v ? (1.f - lx) * mk : 0.f;
        wx1m[k] = x1v ? lx * mk : 0.f;
        float wy0 = y0v ? (1.f - ly) : 0.f;
        float wy1 = y1v ? ly : 0.f;
        int y0c = min(max(y0, 0), 127), x0c = min(max(x0, 0), 127);
        int dxb = (x0 >= 0 && x0 < 127) ? 1 : 0;
        int dyb = (y0 >= 0 && y0 < 127) ? 1 : 0;
        if (quad == 0) {
            ptab[pxl * 9 + k] = ((y0c << 7) + x0c) | (dxb << 14) | (dyb << 15);
            f32x2 wy; wy[0] = wy0; wy[1] = wy1;
            wytab[pxl * 9 + k] = pk2bf(wy);
        }
    }
    __syncthreads();   // all waves past Phase A before gather overwrites buf

    // ========== Phase C: deform MFMA, y-combining gather, 1-tap prefetch ====
    f32x4 acc[4];
#pragma unroll
    for (int ot = 0; ot < 4; ot++) acc[ot] = (f32x4){0.f, 0.f, 0.f, 0.f};

    // gather lane mapping: m = lane + 64*i -> s = m&7, xc = (m>>3)&1,
    // pxn = (m>>4) = (lane>>4) + 4*i
    int s8  = (lane & 7) << 3;          // slice offset (ushorts)
    int xc  = (lane >> 3) & 1;          // x-corner this lane serves
    int pxb = lane >> 4;                // pxn base
    int pib = (pt << 4) * 9;            // wave's ptab base
    unsigned short* gbw = &buf[pt * 2320];          // wave gather region
    int gwoff = xc * 1160 + s8;
    const unsigned short* gbr = &buf[pt * 2320 + n * 72];

    bf16x8 pT[4], pB[4];
#pragma unroll
    for (int i = 0; i < 4; i++) {       // prologue: tap 0 top/bottom rows
        int p = ptab[pib + (pxb + (i << 2)) * 9];
        int row = (p & 0x3FFF) + (xc & ((p >> 14) & 1));
        int dyo = ((p >> 15) & 1) << 7;
        pT[i] = *(const bf16x8*)(xtb + (row << 6) + s8);
        pB[i] = *(const bf16x8*)(xtb + ((row + dyo) << 6) + s8);
    }

#pragma unroll
    for (int tap = 0; tap < 9; tap++) {
        // issue next tap's loads (latency hidden behind this tap's compute)
        bf16x8 nT[4], nB[4];
        if (tap < 8) {
#pragma unroll
            for (int i = 0; i < 4; i++) {
                int p = ptab[pib + (pxb + (i << 2)) * 9 + tap + 1];
                int row = (p & 0x3FFF) + (xc & ((p >> 14) & 1));
                int dyo = ((p >> 15) & 1) << 7;
                nT[i] = *(const bf16x8*)(xtb + (row << 6) + s8);
                nB[i] = *(const bf16x8*)(xtb + ((row + dyo) << 6) + s8);
            }
        }
        // y-combine current tap and write ONE row per (px, x-corner)
#pragma unroll
        for (int i = 0; i < 4; i++) {
            int pxn = pxb + (i << 2);
            unsigned wyp = wytab[pib + pxn * 9 + tap];
            float wy0 = bf2f((unsigned short)(wyp & 0xFFFF));
            float wy1 = bf2f((unsigned short)(wyp >> 16));
            f32x2 Wy0 = {wy0, wy0}, Wy1 = {wy1, wy1};
            const unsigned* ut = (const unsigned*)&pT[i];
            const unsigned* ub = (const unsigned*)&pB[i];
            bf16x8 ov;
            unsigned* uo = (unsigned*)&ov;
#pragma unroll
            for (int jj = 0; jj < 4; jj++)
                uo[jj] = pk2bf(upk2(ut[jj]) * Wy0 + upk2(ub[jj]) * Wy1);
            *(bf16x8*)&gbw[gwoff + pxn * 72] = ov;
        }
        // consume own pixel: 2 y-combined rows, x-weights from registers
        f32x2 Wx0 = {wx0m[tap], wx0m[tap]}, Wx1 = {wx1m[tap], wx1m[tap]};
#pragma unroll
        for (int kk = 0; kk < 2; kk++) {
            int co = (kk << 5) + (quad << 3);
            bf16x8 v0 = *(const bf16x8*)(gbr + co);           // x0 row
            bf16x8 v1 = *(const bf16x8*)(gbr + 1160 + co);    // x1 row
            const unsigned* u0 = (const unsigned*)&v0;
            const unsigned* u1 = (const unsigned*)&v1;
            bf16x8 bfrag;
            unsigned* bu = (unsigned*)&bfrag;
#pragma unroll
            for (int jj = 0; jj < 4; jj++)
                bu[jj] = pk2bf(upk2(u0[jj]) * Wx0 + upk2(u1[jj]) * Wx1);
            int gks = tap * 2 + kk;
#pragma unroll
            for (int ot = 0; ot < 4; ot++) {
                bf16x8 af = *(const bf16x8*)(wpack + ((gks * 4 + ot) * 64 + lane) * 8);
                acc[ot] = __builtin_amdgcn_mfma_f32_16x16x32_bf16(af, bfrag, acc[ot], 0, 0, 0);
            }
        }
        if (tap < 8) {
#pragma unroll
            for (int i = 0; i < 4; i++) { pT[i] = nT[i]; pB[i] = nB[i]; }
        }
    }

    // ---- epilogue: D col(lane&15)=px, row = ot*16 + quad*4 + r = o
    int opix = (h << 7) + px0 + (pt << 4) + n;
#pragma unroll
    for (int ot = 0; ot < 4; ot++) {
#pragma unroll
        for (int r = 0; r < 4; r++) {
            int o = ot * 16 + quad * 4 + r;
            out[(b * 64 + o) * HW + opix] = acc[ot][r] + dbv[o];
        }
    }
}

extern "C" void kernel_launch(void* const* d_in, const int* in_sizes, int n_in,
                              void* d_out, int out_size, void* d_ws, size_t ws_size,
                              hipStream_t stream) {
    const float* x   = (const float*)d_in[0];
    const float* ow  = (const float*)d_in[1];
    const float* ob  = (const float*)d_in[2];
    const float* mw  = (const float*)d_in[3];
    const float* mb  = (const float*)d_in[4];
    const float* dw  = (const float*)d_in[5];
    const float* dbv = (const float*)d_in[6];
    float* out = (float*)d_out;

    unsigned short* wpack  = (unsigned short*)d_ws;          // 36864
    unsigned short* wcpack = wpack + 36864;                  // 18432
    unsigned short* xT     = wpack + 55296;                  // 8388608

    prep_transpose<<<2048, 256, 0, stream>>>(x, ow, mw, dw, wpack, wcpack, xT);
    fused_kernel<<<2048, 256, 0, stream>>>(xT, wcpack, wpack, ob, mb, dbv, out);
}